// Round 5
// baseline (198.911 us; speedup 1.0000x reference)
//
#include <hip/hip_runtime.h>

// RNN: h_s = tanh(X[s,b]*W_ih + b_ih + b_hh + W_hh @ h_{s-1}); y_s = W_out·h_s + b_out
// S=512, B=4096, HID=30.
// One batch element per WAVE. K-split: lanes 0..31 accumulate k=0..15,
// lanes 32..63 accumulate k=16..29 for hidden unit (lane&31); one
// __shfl_xor(32) + add combines halves. Lane 30 carries the W_out row
// (its acc == y). 4096 waves -> 4 waves/SIMD (2x R4's occupancy).
// h-exchange wave-internal via LDS, zero barriers. Depth-4 X prefetch.

#define SEQ 512
#define BATCH 4096
#define HID 30

__global__ __launch_bounds__(256, 4) void rnn_tanh_kernel(
    const float* __restrict__ X,      // [SEQ, BATCH]
    const float* __restrict__ W_ih,   // [HID, 1]
    const float* __restrict__ W_hh,   // [HID, HID]
    const float* __restrict__ b_ih,   // [HID]
    const float* __restrict__ b_hh,   // [HID]
    const float* __restrict__ W_out,  // [1, HID]
    const float* __restrict__ b_out,  // [1]
    float* __restrict__ Y)            // [SEQ, BATCH]
{
  const int tid  = threadIdx.x;
  const int lane = tid & 63;
  const int j    = lane & 31;   // hidden unit (30 = output row, 31 = pad)
  const int half = lane >> 5;   // 0: k=0..15, 1: k=16..29
  const int wid  = tid >> 6;    // wave within block (0..3)
  const int gb   = __builtin_amdgcn_readfirstlane(blockIdx.x * 4 + wid);

  __shared__ float hlds[4][32];

  // Per-lane constants. High half gets wih=bsum=0 so the combine doesn't
  // double-count x*W_ih + bias. Pad weights are 0 -> pad h stays 0/finite.
  float wih = 0.f, bsum = 0.f;
  float w[16];
#pragma unroll
  for (int k = 0; k < 16; ++k) w[k] = 0.f;

  if (j < HID) {
    if (half == 0) {
      wih  = W_ih[j];
      bsum = b_ih[j] + b_hh[j];
#pragma unroll
      for (int k = 0; k < 16; ++k) w[k] = W_hh[j * HID + k];
    } else {
#pragma unroll
      for (int k = 0; k < 14; ++k) w[k] = W_hh[j * HID + 16 + k];
    }
  } else if (j == HID) {        // output projection row
    if (half == 0) {
      bsum = b_out[0];
#pragma unroll
      for (int k = 0; k < 16; ++k) w[k] = W_out[k];
    } else {
#pragma unroll
      for (int k = 0; k < 14; ++k) w[k] = W_out[16 + k];
    }
  }
  // Pin weights in VGPRs (R3 lesson: LICM won't keep them resident otherwise).
#pragma unroll
  for (int k = 0; k < 16; ++k) asm volatile("" : "+v"(w[k]));
  asm volatile("" : "+v"(wih), "+v"(bsum));

  // h_0 = 0. Wave-internal; in-order DS pipe -> no barrier ever needed.
  hlds[wid][j] = 0.f;
  const float* hp = &hlds[wid][half * 16];  // this half's 16 h-slots

  float4 hv0 = *reinterpret_cast<const float4*>(hp + 0);
  float4 hv1 = *reinterpret_cast<const float4*>(hp + 4);
  float4 hv2 = *reinterpret_cast<const float4*>(hp + 8);
  float4 hv3 = *reinterpret_cast<const float4*>(hp + 12);

  // Wave-uniform X column base; depth-4 rotating prefetch.
  const float* Xg = X + gb;
  float x0 = Xg[0 * BATCH];
  float x1 = Xg[1 * BATCH];
  float x2 = Xg[2 * BATCH];
  float x3 = Xg[3 * BATCH];

  auto FMA_PASS = [&](float init) -> float {
    float a0 = init, a1 = 0.f, a2 = 0.f, a3 = 0.f;
    a0 = fmaf(w[0],  hv0.x, a0); a1 = fmaf(w[1],  hv0.y, a1);
    a2 = fmaf(w[2],  hv0.z, a2); a3 = fmaf(w[3],  hv0.w, a3);
    a0 = fmaf(w[4],  hv1.x, a0); a1 = fmaf(w[5],  hv1.y, a1);
    a2 = fmaf(w[6],  hv1.z, a2); a3 = fmaf(w[7],  hv1.w, a3);
    a0 = fmaf(w[8],  hv2.x, a0); a1 = fmaf(w[9],  hv2.y, a1);
    a2 = fmaf(w[10], hv2.z, a2); a3 = fmaf(w[11], hv2.w, a3);
    a0 = fmaf(w[12], hv3.x, a0); a1 = fmaf(w[13], hv3.y, a1);
    a2 = fmaf(w[14], hv3.z, a2); a3 = fmaf(w[15], hv3.w, a3);
    return (a0 + a1) + (a2 + a3);
  };

  auto STEP = [&](int s, float& xreg) {
    // High half: wih=bsum=0 -> init contributes nothing there.
    const float part = FMA_PASS(fmaf(xreg, wih, bsum));
    const int snext = (s + 4 < SEQ) ? s + 4 : SEQ - 1;
    xreg = Xg[snext * BATCH];

    // Combine K-halves: both lanes j and j+32 end with the full pre-activation.
    const float acc = part + __shfl_xor(part, 32, 64);

    // Lane 30's acc is y_{s-1} = W_out·h_{s-1} + b_out.
    if (lane == HID && s != 0) Y[(s - 1) * BATCH + gb] = acc;

    // tanh(t) = 1 - 2/(e^{2t}+1).
    const float t = __builtin_amdgcn_fmed3f(acc, -9.f, 9.f);
    const float e = __builtin_amdgcn_exp2f(t * 2.885390081777927f);  // 2*log2(e)
    const float h = fmaf(-2.f, __builtin_amdgcn_rcpf(e + 1.f), 1.f);

    // Publish h_s (lanes j and j+32 write identical values -> benign 2-way
    // same-data write), then immediately re-issue this half's 4 h reads.
    hlds[wid][j] = h;
    hv0 = *reinterpret_cast<const float4*>(hp + 0);
    hv1 = *reinterpret_cast<const float4*>(hp + 4);
    hv2 = *reinterpret_cast<const float4*>(hp + 8);
    hv3 = *reinterpret_cast<const float4*>(hp + 12);
  };

  for (int s = 0; s < SEQ; s += 4) {
    STEP(s + 0, x0);
    STEP(s + 1, x1);
    STEP(s + 2, x2);
    STEP(s + 3, x3);
  }

  // Epilogue: hv holds h_{SEQ-1}; lane 30's combined dot is y_{SEQ-1}.
  const float part = FMA_PASS(bsum);
  const float acc = part + __shfl_xor(part, 32, 64);
  if (lane == HID) Y[(SEQ - 1) * BATCH + gb] = acc;
}

extern "C" void kernel_launch(void* const* d_in, const int* in_sizes, int n_in,
                              void* d_out, int out_size, void* d_ws, size_t ws_size,
                              hipStream_t stream) {
  const float* X     = (const float*)d_in[0];
  const float* W_ih  = (const float*)d_in[1];
  const float* W_hh  = (const float*)d_in[2];
  const float* b_ih  = (const float*)d_in[3];
  const float* b_hh  = (const float*)d_in[4];
  const float* W_out = (const float*)d_in[5];
  const float* b_out = (const float*)d_in[6];
  float* Y = (float*)d_out;

  // One batch element per wave: 4096 waves, 4 per 256-thread block.
  dim3 grid(BATCH / 4), block(256);
  rnn_tanh_kernel<<<grid, block, 0, stream>>>(X, W_ih, W_hh, b_ih, b_hh,
                                              W_out, b_out, Y);
}

// Round 6
// 124.655 us; speedup vs baseline: 1.5957x; 1.5957x over previous
//
#include <hip/hip_runtime.h>

// RNN: h_s = tanh(X[s,b]*W_ih + b_ih + b_hh + W_hh @ h_{s-1}); y_s = W_out·h_s + b_out
// S=512, B=4096, HID=30.
// One batch element per WAVE; lanes paired: j = lane>>1 (hidden unit, 30 =
// output row, 31 = pad), half = lane&1 selects k-half (0..15 / 16..31 with
// k=30,31 zero-weighted). K-combine = quad_perm DPP swap (lane^1, pure VALU).
// 4096 waves -> 4 waves/SIMD. h-exchange wave-internal via LDS, zero barriers.
// X loads stay per-lane vector loads (R5 lesson: readfirstlane -> s_load ->
// SMEM shares lgkmcnt with DS -> prefetch latency lands on the h-read waits).

#define SEQ 512
#define BATCH 4096
#define HID 30

template <int CTRL>
__device__ __forceinline__ float dpp_add(float x) {
  int moved = __builtin_amdgcn_update_dpp(0, __float_as_int(x), CTRL, 0xf, 0xf, true);
  return x + __int_as_float(moved);
}

__global__ __attribute__((amdgpu_flat_work_group_size(256, 256),
                          amdgpu_waves_per_eu(4, 4)))
void rnn_tanh_kernel(
    const float* __restrict__ X,      // [SEQ, BATCH]
    const float* __restrict__ W_ih,   // [HID, 1]
    const float* __restrict__ W_hh,   // [HID, HID]
    const float* __restrict__ b_ih,   // [HID]
    const float* __restrict__ b_hh,   // [HID]
    const float* __restrict__ W_out,  // [1, HID]
    const float* __restrict__ b_out,  // [1]
    float* __restrict__ Y)            // [SEQ, BATCH]
{
  const int tid  = threadIdx.x;
  const int lane = tid & 63;
  const int j    = lane >> 1;        // hidden unit (30 = output row, 31 = pad)
  const int half = lane & 1;         // 0: k=0..15, 1: k=16..31
  const int k0   = half << 4;
  const int wid  = tid >> 6;         // wave within block (0..3)
  const int gb   = blockIdx.x * 4 + wid;  // batch element (per-lane -> vector loads)

  __shared__ float hlds[4][32];

  // Per-lane constants. Odd (half=1) lanes get wih=bsum=0 so the pair-combine
  // doesn't double-count x*W_ih + bias. k=30,31 weights are 0.
  float wih = 0.f, bsum = 0.f;
  float w[16];
#pragma unroll
  for (int k = 0; k < 16; ++k) w[k] = 0.f;

  if (j < HID) {
    if (half == 0) {
      wih  = W_ih[j];
      bsum = b_ih[j] + b_hh[j];
    }
#pragma unroll
    for (int k = 0; k < 16; ++k) {
      const int kk = k0 + k;
      if (kk < HID) w[k] = W_hh[j * HID + kk];
    }
  } else if (j == HID) {             // output projection row -> y needs no reduce
    if (half == 0) bsum = b_out[0];
#pragma unroll
    for (int k = 0; k < 16; ++k) {
      const int kk = k0 + k;
      if (kk < HID) w[k] = W_out[kk];
    }
  }
  // Pin weights into arch VGPRs (R3 lesson: LICM won't keep them resident).
#pragma unroll
  for (int k = 0; k < 16; ++k) asm volatile("" : "+v"(w[k]));
  asm volatile("" : "+v"(wih), "+v"(bsum));

  // h_0 = 0. Paired lanes write the same address with the same value (benign).
  hlds[wid][j] = 0.f;
  const float* hp = &hlds[wid][k0];  // this half's 16 h-slots

  float4 hv0 = *reinterpret_cast<const float4*>(hp + 0);
  float4 hv1 = *reinterpret_cast<const float4*>(hp + 4);
  float4 hv2 = *reinterpret_cast<const float4*>(hp + 8);
  float4 hv3 = *reinterpret_cast<const float4*>(hp + 12);

  // Depth-4 rotating X prefetch; per-lane addresses -> global_load (vmcnt).
  const float* Xg = X + gb;
  float x0 = Xg[0 * BATCH];
  float x1 = Xg[1 * BATCH];
  float x2 = Xg[2 * BATCH];
  float x3 = Xg[3 * BATCH];

  auto FMA_PASS = [&](float init) -> float {
    float a0 = init, a1 = 0.f, a2 = 0.f, a3 = 0.f;
    a0 = fmaf(w[0],  hv0.x, a0); a1 = fmaf(w[1],  hv0.y, a1);
    a2 = fmaf(w[2],  hv0.z, a2); a3 = fmaf(w[3],  hv0.w, a3);
    a0 = fmaf(w[4],  hv1.x, a0); a1 = fmaf(w[5],  hv1.y, a1);
    a2 = fmaf(w[6],  hv1.z, a2); a3 = fmaf(w[7],  hv1.w, a3);
    a0 = fmaf(w[8],  hv2.x, a0); a1 = fmaf(w[9],  hv2.y, a1);
    a2 = fmaf(w[10], hv2.z, a2); a3 = fmaf(w[11], hv2.w, a3);
    a0 = fmaf(w[12], hv3.x, a0); a1 = fmaf(w[13], hv3.y, a1);
    a2 = fmaf(w[14], hv3.z, a2); a3 = fmaf(w[15], hv3.w, a3);
    return (a0 + a1) + (a2 + a3);
  };

  auto STEP = [&](int s, float& xreg) {
    const float part = FMA_PASS(fmaf(xreg, wih, bsum));
    const int snext = (s + 4 < SEQ) ? s + 4 : SEQ - 1;
    xreg = Xg[snext * BATCH];

    // Pair-combine via quad_perm [1,0,3,2] (lane^1 swap) on the VALU pipe.
    // IEEE add is commutative -> both lanes of a pair get bit-identical acc.
    const float acc = dpp_add<0xB1>(part);

    // Lane 60 (j=30, half=0): acc == y_{s-1} = W_out·h_{s-1} + b_out.
    if (lane == 2 * HID && s != 0) Y[(s - 1) * BATCH + gb] = acc;

    // tanh(t) = 1 - 2/(e^{2t}+1).
    const float t = __builtin_amdgcn_fmed3f(acc, -9.f, 9.f);
    const float e = __builtin_amdgcn_exp2f(t * 2.885390081777927f);  // 2*log2(e)
    const float h = fmaf(-2.f, __builtin_amdgcn_rcpf(e + 1.f), 1.f);

    // Publish h_s (paired lanes write identical value -> benign), then
    // immediately re-issue this half's 4 h reads (DS pipe is in-order
    // wave-internally -> no barrier).
    hlds[wid][j] = h;
    hv0 = *reinterpret_cast<const float4*>(hp + 0);
    hv1 = *reinterpret_cast<const float4*>(hp + 4);
    hv2 = *reinterpret_cast<const float4*>(hp + 8);
    hv3 = *reinterpret_cast<const float4*>(hp + 12);
  };

  for (int s = 0; s < SEQ; s += 4) {
    STEP(s + 0, x0);
    STEP(s + 1, x1);
    STEP(s + 2, x2);
    STEP(s + 3, x3);
  }

  // Epilogue: hv holds h_{SEQ-1}; lane 60's combined dot is y_{SEQ-1}.
  const float part = FMA_PASS(bsum);
  const float acc = dpp_add<0xB1>(part);
  if (lane == 2 * HID) Y[(SEQ - 1) * BATCH + gb] = acc;
}

extern "C" void kernel_launch(void* const* d_in, const int* in_sizes, int n_in,
                              void* d_out, int out_size, void* d_ws, size_t ws_size,
                              hipStream_t stream) {
  const float* X     = (const float*)d_in[0];
  const float* W_ih  = (const float*)d_in[1];
  const float* W_hh  = (const float*)d_in[2];
  const float* b_ih  = (const float*)d_in[3];
  const float* b_hh  = (const float*)d_in[4];
  const float* W_out = (const float*)d_in[5];
  const float* b_out = (const float*)d_in[6];
  float* Y = (float*)d_out;

  // One batch element per wave: 4096 waves, 4 per 256-thread block.
  dim3 grid(BATCH / 4), block(256);
  rnn_tanh_kernel<<<grid, block, 0, stream>>>(X, W_ih, W_hh, b_ih, b_hh,
                                              W_out, b_out, Y);
}